// Round 20
// baseline (204.721 us; speedup 1.0000x reference)
//
#include <hip/hip_runtime.h>
#include <hip/hip_bf16.h>

#define NNODE 50000
#define NEDGE 640000
#define NREL  3
#define HIDD  128
#define GNUM  512
#define K1M   128   // layer-1 GEMM K (99 used + pad to 128 for MFMA)
#define K2    512   // layer-2 GEMM K (3*128 relations + 128 root)
#define NB    196   // scan blocks = ceil(NNODE/256)
#define EQ    (NEDGE / 4)           // 160000 edges per ILP batch
#define CNT_BLOCKS ((EQ + 255) / 256)                       // 625
#define TAB_BLOCKS ((K1M * 128 + 33 * 128 + K2 * 128 + 255) / 256)  // 338

typedef float  f32x4   __attribute__((ext_vector_type(4)));
typedef short  vshort8 __attribute__((ext_vector_type(8)));

// swizzled k-block position within a 32-short sub-row (MFMA LDS, conflict-free)
#define SWZ(row, kb) ((((kb) ^ (((row) >> 1) & 3)) << 3))

__device__ __forceinline__ short bf16_rne(float f) {
    unsigned u = __float_as_uint(f);
    return (short)((u + 0x7FFFu + ((u >> 16) & 1u)) >> 16);
}

// ---------------- merged: edge counting (rank atomics, 4/thread) + nf pack + weight builder ----------------
__global__ void count_build_kernel(const int* __restrict__ ei, const int* __restrict__ et,
                                   const int* __restrict__ shape_id, const int* __restrict__ color_id,
                                   const float* __restrict__ pos,
                                   int* __restrict__ cnt, int* __restrict__ rank,
                                   int2* __restrict__ nf,
                                   const float* __restrict__ shape_w, const float* __restrict__ color_w,
                                   const float* __restrict__ W1, const float* __restrict__ root1,
                                   const float* __restrict__ W2, const float* __restrict__ root2,
                                   short* __restrict__ B1th, float* __restrict__ rootTab,
                                   short* __restrict__ Bt_hi) {
    if (blockIdx.x < CNT_BLOCKS) {
        int tid = blockIdx.x * blockDim.x + threadIdx.x;   // 0..EQ-1
        if (tid < NNODE) nf[tid] = make_int2(shape_id[tid] | (color_id[tid] << 8), __float_as_int(pos[tid]));
        if (tid >= EQ) return;
        int e0 = tid, e1 = tid + EQ, e2 = tid + 2 * EQ, e3 = tid + 3 * EQ;
        int d0 = ei[NEDGE + e0], d1 = ei[NEDGE + e1], d2 = ei[NEDGE + e2], d3 = ei[NEDGE + e3];
        int r0 = et[e0], r1 = et[e1], r2 = et[e2], r3 = et[e3];
        int k0 = atomicAdd(&cnt[d0 * 3 + r0], 1);
        int k1 = atomicAdd(&cnt[d1 * 3 + r1], 1);
        int k2 = atomicAdd(&cnt[d2 * 3 + r2], 1);
        int k3 = atomicAdd(&cnt[d3 * 3 + r3], 1);
        rank[e0] = k0; rank[e1] = k1; rank[e2] = k2; rank[e3] = k3;
        return;
    }
    int idx = (blockIdx.x - CNT_BLOCKS) * blockDim.x + threadIdx.x;
    if (idx < K1M * 128) {                    // B1th[n][k]
        int k = idx >> 7, n = idx & 127;
        float v = 0.f;
        if (k < 99) {
            int r = k / 33, j = k - r * 33;
            const float* Wsrc = W1 + (size_t)r * 129 * 128;
            if (j < 16) {
                for (int e = 0; e < 64; ++e) v += shape_w[j * 64 + e] * Wsrc[e * 128 + n];
            } else if (j < 32) {
                int c = j - 16;
                for (int e = 0; e < 64; ++e) v += color_w[c * 64 + e] * Wsrc[(64 + e) * 128 + n];
            } else {
                v = Wsrc[128 * 128 + n];
            }
        }
        B1th[(size_t)n * K1M + k] = bf16_rne(v);
        return;
    }
    int idx2 = idx - K1M * 128;
    if (idx2 < 33 * 128) {                    // rootTab[j][h]
        int h = idx2 & 127, j = idx2 >> 7;
        float v;
        if (j < 16) {
            v = 0.f;
            for (int e = 0; e < 64; ++e) v += shape_w[j * 64 + e] * root1[e * 128 + h];
        } else if (j < 32) {
            int c = j - 16;
            v = 0.f;
            for (int e = 0; e < 64; ++e) v += color_w[c * 64 + e] * root1[(64 + e) * 128 + h];
        } else {
            v = root1[128 * 128 + h];
        }
        rootTab[j * 128 + h] = v;
        return;
    }
    int idx3 = idx2 - 33 * 128;               // Bt_hi[n][k] (B2 transposed)
    if (idx3 >= K2 * 128) return;
    int k = idx3 >> 7, n = idx3 & 127;
    float v = (k < 384) ? W2[idx3] : root2[idx3 - 384 * 128];
    Bt_hi[(size_t)n * K2 + k] = bf16_rne(v);
}

// ---------------- prefix scan (2-phase), relation-major CSR; also zeroes pooled ----------------
__global__ void scan_partial_kernel(const int* __restrict__ cnt, int* __restrict__ partial,
                                    float* __restrict__ pooled) {
    __shared__ int sh[256];
    int t = threadIdx.x, i = blockIdx.x * 256 + t;
    for (int z = i; z < GNUM * 128; z += NB * 256) pooled[z] = 0.f;
    int v = (i < NNODE) ? cnt[3 * i] + cnt[3 * i + 1] + cnt[3 * i + 2] : 0;
    sh[t] = v; __syncthreads();
    for (int o = 128; o > 0; o >>= 1) { if (t < o) sh[t] += sh[t + o]; __syncthreads(); }
    if (t == 0) partial[blockIdx.x] = sh[0];
}

// merged mid+final: each block redundantly scans the 196 partials in LDS
__global__ void scan_final_kernel(const int* __restrict__ cnt, const int* __restrict__ partial,
                                  int* __restrict__ offs3, float* __restrict__ rcnt) {
    __shared__ int shp[256];
    __shared__ int sh[256];
    int t = threadIdx.x, i = blockIdx.x * 256 + t;
    int pv = (t < NB) ? partial[t] : 0;
    shp[t] = pv; __syncthreads();
    for (int o = 1; o < 256; o <<= 1) {
        int x = (t >= o) ? shp[t - o] : 0; __syncthreads();
        shp[t] += x; __syncthreads();
    }
    int blockOff = (blockIdx.x > 0) ? shp[blockIdx.x - 1] : 0;
    int c0 = 0, c1 = 0, c2 = 0;
    if (i < NNODE) { c0 = cnt[3 * i]; c1 = cnt[3 * i + 1]; c2 = cnt[3 * i + 2]; }
    int v = c0 + c1 + c2;
    sh[t] = v; __syncthreads();
    for (int o = 1; o < 256; o <<= 1) {
        int x = (t >= o) ? sh[t - o] : 0; __syncthreads();
        sh[t] += x; __syncthreads();
    }
    int exc = sh[t] - v + blockOff;
    if (i < NNODE) {
        offs3[3 * i]     = exc;
        offs3[3 * i + 1] = exc + c0;
        offs3[3 * i + 2] = exc + c0 + c1;
        float4 rc = make_float4(1.f / fmaxf((float)c0, 1.f), 1.f / fmaxf((float)c1, 1.f),
                                1.f / fmaxf((float)c2, 1.f), 1.f);
        *(float4*)&rcnt[i * 4] = rc;
    }
    if (blockIdx.x == 0 && t == 0) offs3[3 * NNODE] = NEDGE;
}

// ---------------- fill: atomic-free, 4 edges/thread ----------------
__global__ void fill_kernel(const int* __restrict__ ei, const int* __restrict__ et,
                            const int* __restrict__ rank, const int* __restrict__ offs3,
                            int* __restrict__ sorted) {
    int tid = blockIdx.x * blockDim.x + threadIdx.x;   // 0..EQ-1
    if (tid >= EQ) return;
    int e0 = tid, e1 = tid + EQ, e2 = tid + 2 * EQ, e3 = tid + 3 * EQ;
    int s0 = ei[e0], s1 = ei[e1], s2 = ei[e2], s3 = ei[e3];
    int d0 = ei[NEDGE + e0], d1 = ei[NEDGE + e1], d2 = ei[NEDGE + e2], d3 = ei[NEDGE + e3];
    int r0 = et[e0], r1 = et[e1], r2 = et[e2], r3 = et[e3];
    int k0 = rank[e0], k1 = rank[e1], k2 = rank[e2], k3 = rank[e3];
    int p0 = offs3[d0 * 3 + r0] + k0;
    int p1 = offs3[d1 * 3 + r1] + k1;
    int p2 = offs3[d2 * 3 + r2] + k2;
    int p3 = offs3[d3 * 3 + r3] + k3;
    sorted[p0] = s0 | (r0 << 16);
    sorted[p1] = s1 | (r1 << 16);
    sorted[p2] = s2 | (r2 << 16);
    sorted[p3] = s3 | (r3 << 16);
}

// ---------------- layer-1 histogram: 16 lanes/node, 16 nodes/block ----------------
__global__ __launch_bounds__(256) void hist1_kernel(const int* __restrict__ offs3,
                                                    const int* __restrict__ sorted,
                                                    const int2* __restrict__ nf,
                                                    const float* __restrict__ rcnt,
                                                    unsigned short* __restrict__ A1h) {
    __shared__ float hist[16][102];
    int t = threadIdx.x;
    int sub = t >> 4;          // node slot 0..15
    int lane16 = t & 15;
    int d = blockIdx.x * 16 + sub;
    float* hf = hist[sub];
#pragma unroll
    for (int z = lane16; z < 102; z += 16) hf[z] = 0.f;
    if (d < NNODE) {
        int beg = offs3[3 * d], end = offs3[3 * d + 3];
        for (int i = beg + lane16; i < end; i += 16) {
            int w = sorted[i];
            int s = w & 0xFFFF, r = (w >> 16) & 3;
            int2 f = nf[s];
            atomicAdd(&hf[r * 34 + (f.x & 0xFF)], 1.f);
            atomicAdd(&hf[r * 34 + 16 + (f.x >> 8)], 1.f);
            atomicAdd(&hf[r * 34 + 32], __int_as_float(f.y));
        }
        float rc0 = rcnt[d * 4 + 0], rc1 = rcnt[d * 4 + 1], rc2 = rcnt[d * 4 + 2];
        vshort8 outv;
#pragma unroll
        for (int j = 0; j < 8; ++j) {
            int slot = lane16 * 8 + j;                  // 0..127
            float v = 0.f;
            if (slot < 99) {
                int r = slot / 33;
                float rc = (r == 0) ? rc0 : ((r == 1) ? rc1 : rc2);
                v = hf[r * 34 + (slot - r * 33)] * rc;
            }
            outv[j] = bf16_rne(v);
        }
        *(vshort8*)&A1h[(size_t)d * K1M + lane16 * 8] = outv;
    }
}

// ---------------- layer-1 GEMM: MFMA bf16 AhxBh, BM=64, swizzled LDS; writes compact x1b ----------------
__global__ __launch_bounds__(256) void gemm1_mfma_kernel(
    const unsigned short* __restrict__ A1h,
    const short* __restrict__ B1th,
    const int* __restrict__ shape_id, const int* __restrict__ color_id,
    const float* __restrict__ pos, const float* __restrict__ rootTab,
    const float* __restrict__ bias,
    unsigned short* __restrict__ x1b) {
    __shared__ short Ah[64][32];
    __shared__ short Bh[128][32];
    const int t    = threadIdx.x;
    const int lane = t & 63;
    const int w    = t >> 6;
    const int wm   = w >> 1, wn = w & 1;     // wave tile 32(M) x 64(N)
    const int bm0  = blockIdx.x * 64;
    const int lr   = lane & 15, lk = lane >> 4;
    const int sr = t >> 2, skb = t & 3;
    int gra = bm0 + sr; if (gra >= NNODE) gra = NNODE - 1;   // clamp (C-write guarded)
    f32x4 acc[2][4] = {};
    for (int kt = 0; kt < K1M; kt += 32) {
        vshort8 avh = *(const vshort8*)&A1h[(size_t)gra * K1M + kt + skb * 8];
        vshort8 bvh0 = *(const vshort8*)&B1th[(size_t)sr * K1M + kt + skb * 8];
        vshort8 bvh1 = *(const vshort8*)&B1th[(size_t)(sr + 64) * K1M + kt + skb * 8];
        __syncthreads();
        *(vshort8*)&Ah[sr][SWZ(sr, skb)]           = avh;
        *(vshort8*)&Bh[sr][SWZ(sr, skb)]           = bvh0;
        *(vshort8*)&Bh[sr + 64][SWZ(sr + 64, skb)] = bvh1;
        __syncthreads();
        vshort8 afh[2], bfh[4];
#pragma unroll
        for (int mf = 0; mf < 2; ++mf) {
            int row = wm * 32 + mf * 16 + lr;
            afh[mf] = *(const vshort8*)&Ah[row][SWZ(row, lk)];
        }
#pragma unroll
        for (int nf2 = 0; nf2 < 4; ++nf2) {
            int row = wn * 64 + nf2 * 16 + lr;
            bfh[nf2] = *(const vshort8*)&Bh[row][SWZ(row, lk)];
        }
#pragma unroll
        for (int mf = 0; mf < 2; ++mf)
#pragma unroll
            for (int nf2 = 0; nf2 < 4; ++nf2)
                acc[mf][nf2] = __builtin_amdgcn_mfma_f32_16x16x32_bf16(afh[mf], bfh[nf2], acc[mf][nf2], 0, 0, 0);
    }
    // epilogue: + root lookups + bias, relu, write compact x1b (bf16-hi)
#pragma unroll
    for (int mf = 0; mf < 2; ++mf) {
        int mb = bm0 + wm * 32 + mf * 16 + (lane >> 4) * 4;
#pragma unroll
        for (int r = 0; r < 4; ++r) {
            int gm = mb + r;
            if (gm >= NNODE) continue;
            int sid = shape_id[gm], cid = color_id[gm];
            float pv = pos[gm];
#pragma unroll
            for (int nf2 = 0; nf2 < 4; ++nf2) {
                int n = wn * 64 + nf2 * 16 + lr;
                float v = acc[mf][nf2][r] + rootTab[sid * 128 + n] + rootTab[(16 + cid) * 128 + n]
                        + pv * rootTab[32 * 128 + n] + bias[n];
                x1b[(size_t)gm * 128 + n] = (unsigned short)bf16_rne(fmaxf(v, 0.f));
            }
        }
    }
}

// ---------------- FUSED layer-2: aggregate (means -> LDS) + MFMA GEMM + pool epilogue ----------------
// block = 64 nodes; phase A: 4 waves aggregate 16 nodes each into swizzled LDS A-tile + copy
// root block from x1b; phase B: K-loop over 512 (A from LDS, B staged); epilogue: pool reduce.
__global__ __launch_bounds__(256) void layer2_kernel(
    const int* __restrict__ offs3, const int* __restrict__ sorted,
    const float* __restrict__ rcnt, const unsigned short* __restrict__ x1b,
    const short* __restrict__ Bt_hi, const float* __restrict__ bias,
    const int* __restrict__ batch, float* __restrict__ pooled) {
    __shared__ char smem[64 * 512 * 2 + 128 * 32 * 2 + 256];   // 72.3 KB
    short (*A2t)[512] = (short(*)[512])smem;                   // 64 KB A-tile (swizzled)
    short (*Bh)[32]   = (short(*)[32])(smem + 65536);          // 8 KB
    int*  batchLDS    = (int*)(smem + 65536 + 8192);
    float (*Cst)[132] = (float(*)[132])smem;                   // overlay after K-loop
    const int t    = threadIdx.x;
    const int lane = t & 63;
    const int w    = t >> 6;
    const int wm   = w >> 1, wn = w & 1;
    const int bm0  = blockIdx.x * 64;
    const int lr   = lane & 15, lk = lane >> 4;
    const unsigned* xp = (const unsigned*)x1b;    // row = 64 uints (128 bf16)

    // ---- phase A: each wave aggregates 16 nodes ----
    for (int li = 0; li < 16; ++li) {
        int row = w * 16 + li;
        int d = bm0 + row;
        if (d >= NNODE) break;
        int b0  = __builtin_amdgcn_readfirstlane(offs3[3 * d]);
        int b1  = __builtin_amdgcn_readfirstlane(offs3[3 * d + 1]);
        int b2  = __builtin_amdgcn_readfirstlane(offs3[3 * d + 2]);
        int end = __builtin_amdgcn_readfirstlane(offs3[3 * d + 3]);
        float a00 = 0.f, a01 = 0.f, a10 = 0.f, a11 = 0.f, a20 = 0.f, a21 = 0.f;
#define AGG_ACC(ii, x) {                                            \
        float lo_ = __uint_as_float((x) << 16);                     \
        float hi_ = __uint_as_float((x) & 0xFFFF0000u);             \
        if ((ii) >= b2)      { a20 += lo_; a21 += hi_; }            \
        else if ((ii) >= b1) { a10 += lo_; a11 += hi_; }            \
        else                 { a00 += lo_; a01 += hi_; } }
#define AGG_LD(j)  unsigned x##j = xp[((size_t)(unsigned)(sorted[i + j] & 0xFFFF) << 6) + lane]
        int i = b0;
        for (; i + 8 <= end; i += 8) {
            AGG_LD(0); AGG_LD(1); AGG_LD(2); AGG_LD(3);
            AGG_LD(4); AGG_LD(5); AGG_LD(6); AGG_LD(7);
            AGG_ACC(i, x0); AGG_ACC(i + 1, x1); AGG_ACC(i + 2, x2); AGG_ACC(i + 3, x3);
            AGG_ACC(i + 4, x4); AGG_ACC(i + 5, x5); AGG_ACC(i + 6, x6); AGG_ACC(i + 7, x7);
        }
        for (; i + 4 <= end; i += 4) {
            AGG_LD(0); AGG_LD(1); AGG_LD(2); AGG_LD(3);
            AGG_ACC(i, x0); AGG_ACC(i + 1, x1); AGG_ACC(i + 2, x2); AGG_ACC(i + 3, x3);
        }
        for (; i < end; ++i) {
            AGG_LD(0);
            AGG_ACC(i, x0);
        }
#undef AGG_LD
#undef AGG_ACC
        float rc0 = rcnt[d * 4 + 0], rc1 = rcnt[d * 4 + 1], rc2 = rcnt[d * 4 + 2];
        // write means into swizzled LDS: col0 = rel*128 + lane*2 (2 shorts per lane)
#define AGG_ST(vA, vB, rel) {                                                 \
        int col0 = (rel) * 128 + (lane << 1);                                 \
        int phys = ((col0 >> 5) << 5) + SWZ(row, (col0 >> 3) & 3) + (col0 & 7); \
        unsigned short h0_ = (unsigned short)bf16_rne(vA);                    \
        unsigned short h1_ = (unsigned short)bf16_rne(vB);                    \
        *(unsigned*)&A2t[row][phys] = (unsigned)h0_ | ((unsigned)h1_ << 16); }
        AGG_ST(a00 * rc0, a01 * rc0, 0);
        AGG_ST(a10 * rc1, a11 * rc1, 1);
        AGG_ST(a20 * rc2, a21 * rc2, 2);
#undef AGG_ST
    }
    // ---- root-block copy: cols 384..511 from x1b, swizzled; t -> (row = t>>2, q = t&3) ----
    {
        int row = t >> 2, q = t & 3;
        int grow = bm0 + row; if (grow >= NNODE) grow = NNODE - 1;
#pragma unroll
        for (int kb = 0; kb < 4; ++kb) {
            vshort8 v = *(const vshort8*)&x1b[(size_t)grow * 128 + q * 32 + kb * 8];
            *(vshort8*)&A2t[row][(12 + q) * 32 + SWZ(row, kb)] = v;
        }
    }
    // ---- phase B: K-loop, A from LDS, B staged from global ----
    const int sr = t >> 2, skb = t & 3;
    f32x4 acc[2][4] = {};
    for (int kt = 0; kt < K2; kt += 32) {
        vshort8 bvh0 = *(const vshort8*)&Bt_hi[(size_t)sr * K2 + kt + skb * 8];
        vshort8 bvh1 = *(const vshort8*)&Bt_hi[(size_t)(sr + 64) * K2 + kt + skb * 8];
        __syncthreads();   // first iter: phase A complete; later: Bh reads done
        *(vshort8*)&Bh[sr][SWZ(sr, skb)]           = bvh0;
        *(vshort8*)&Bh[sr + 64][SWZ(sr + 64, skb)] = bvh1;
        __syncthreads();
        vshort8 afh[2], bfh[4];
#pragma unroll
        for (int mf = 0; mf < 2; ++mf) {
            int row = wm * 32 + mf * 16 + lr;
            afh[mf] = *(const vshort8*)&A2t[row][kt + SWZ(row, lk)];
        }
#pragma unroll
        for (int nf2 = 0; nf2 < 4; ++nf2) {
            int row = wn * 64 + nf2 * 16 + lr;
            bfh[nf2] = *(const vshort8*)&Bh[row][SWZ(row, lk)];
        }
#pragma unroll
        for (int mf = 0; mf < 2; ++mf)
#pragma unroll
            for (int nf2 = 0; nf2 < 4; ++nf2)
                acc[mf][nf2] = __builtin_amdgcn_mfma_f32_16x16x32_bf16(afh[mf], bfh[nf2], acc[mf][nf2], 0, 0, 0);
    }
    __syncthreads();   // all A2t/Bh reads done; reuse smem as Cst
    // ---- epilogue: stage relu(C) to LDS, pool-reduce ----
#pragma unroll
    for (int mf = 0; mf < 2; ++mf) {
        int rb = wm * 32 + mf * 16 + (lane >> 4) * 4;
#pragma unroll
        for (int nf2 = 0; nf2 < 4; ++nf2) {
            int n = wn * 64 + nf2 * 16 + lr;
            float bn = bias[n];
#pragma unroll
            for (int r = 0; r < 4; ++r)
                Cst[rb + r][n] = fmaxf(acc[mf][nf2][r] + bn, 0.f);
        }
    }
    if (t < 64) batchLDS[t] = (bm0 + t < NNODE) ? batch[bm0 + t] : -1;
    __syncthreads();
    {
        int col  = t & 127;
        int rbeg = (t >> 7) * 32;
        float accp = 0.f;
        int cur = batchLDS[rbeg];
        for (int rr = 0; rr < 32; ++rr) {
            int row = rbeg + rr;
            int g = batchLDS[row];
            if (g != cur) {
                if (cur >= 0) atomicAdd(&pooled[cur * 128 + col], accp);
                accp = 0.f; cur = g;
            }
            if (g >= 0) accp += Cst[row][col];
        }
        if (cur >= 0) atomicAdd(&pooled[cur * 128 + col], accp);
    }
}

// ---------------- final: per-graph count via binary search on sorted batch ----------------
__global__ void final_kernel(const float* __restrict__ pooled, const int* __restrict__ batch,
                             const float* __restrict__ lin_w, const float* __restrict__ lin_b,
                             float* __restrict__ out) {
    int idx = blockIdx.x * blockDim.x + threadIdx.x;
    if (idx >= GNUM * 4) return;
    int g = idx >> 2, c = idx & 3;
    int lo = 0, hi = NNODE;
    while (lo < hi) { int m = (lo + hi) >> 1; if (batch[m] < g) lo = m + 1; else hi = m; }
    int lo2 = lo, hi2 = NNODE;
    while (lo2 < hi2) { int m = (lo2 + hi2) >> 1; if (batch[m] < g + 1) lo2 = m + 1; else hi2 = m; }
    float cntf = (float)max(lo2 - lo, 1);
    float dot = 0.f;
    for (int k = 0; k < 128; ++k) dot += pooled[g * 128 + k] * lin_w[k * 4 + c];
    out[idx] = dot / cntf + lin_b[c];
}

// ---------------- launch ----------------
extern "C" void kernel_launch(void* const* d_in, const int* in_sizes, int n_in,
                              void* d_out, int out_size, void* d_ws, size_t ws_size,
                              hipStream_t stream) {
    const float* pos      = (const float*)d_in[0];
    const int*   shape_id = (const int*)d_in[1];
    const int*   color_id = (const int*)d_in[2];
    const int*   ei       = (const int*)d_in[3];
    const int*   et       = (const int*)d_in[4];
    const int*   batch    = (const int*)d_in[5];
    const float* shape_w  = (const float*)d_in[6];
    const float* color_w  = (const float*)d_in[7];
    const float* W1       = (const float*)d_in[8];
    const float* root1    = (const float*)d_in[9];
    const float* b1       = (const float*)d_in[10];
    const float* W2       = (const float*)d_in[11];
    const float* root2    = (const float*)d_in[12];
    const float* b2       = (const float*)d_in[13];
    const float* lin_w    = (const float*)d_in[14];
    const float* lin_b    = (const float*)d_in[15];
    float* out = (float*)d_out;

    char* p = (char*)d_ws;
    auto alloc = [&](size_t bytes) { char* r = p; p += (bytes + 255) & ~(size_t)255; return r; };
    int*   cnt     = (int*)alloc((size_t)NNODE * 3 * 4);
    unsigned short* A1h = (unsigned short*)alloc((size_t)NNODE * K1M * 2);
    float* rcntBuf = (float*)alloc((size_t)NNODE * 4 * 4);
    unsigned short* x1b = (unsigned short*)alloc((size_t)NNODE * 128 * 2);
    float* rootTab = (float*)alloc((size_t)33 * 128 * 4);
    short* B1th    = (short*)alloc((size_t)128 * K1M * 2);
    short* Bt_hi   = (short*)alloc((size_t)128 * K2 * 2);
    float* pooled  = (float*)alloc((size_t)GNUM * 128 * 4);
    int2*  nfTab   = (int2*)alloc((size_t)NNODE * 8);
    int*   sorted  = (int*)alloc((size_t)NEDGE * 4);
    int*   offs3   = (int*)alloc((size_t)(3 * NNODE + 1) * 4);
    int*   rank    = (int*)alloc((size_t)NEDGE * 4);
    int*   partial = (int*)alloc((size_t)NB * 4);

    hipMemsetAsync(cnt, 0, (size_t)NNODE * 3 * 4, stream);

    count_build_kernel<<<CNT_BLOCKS + TAB_BLOCKS, 256, 0, stream>>>(
        ei, et, shape_id, color_id, pos, cnt, rank, nfTab,
        shape_w, color_w, W1, root1, W2, root2, B1th, rootTab, Bt_hi);

    scan_partial_kernel<<<NB, 256, 0, stream>>>(cnt, partial, pooled);
    scan_final_kernel<<<NB, 256, 0, stream>>>(cnt, partial, offs3, rcntBuf);
    fill_kernel<<<(EQ + 255) / 256, 256, 0, stream>>>(ei, et, rank, offs3, sorted);

    hist1_kernel<<<(NNODE + 15) / 16, 256, 0, stream>>>(offs3, sorted, nfTab, rcntBuf, A1h);

    gemm1_mfma_kernel<<<(NNODE + 63) / 64, 256, 0, stream>>>(
        A1h, B1th, shape_id, color_id, pos, rootTab, b1, x1b);

    layer2_kernel<<<(NNODE + 63) / 64, 256, 0, stream>>>(
        offs3, sorted, rcntBuf, x1b, Bt_hi, b2, batch, pooled);

    final_kernel<<<(GNUM * 4 + 255) / 256, 256, 0, stream>>>(
        pooled, batch, lin_w, lin_b, out);
}

// Round 21
// 148.032 us; speedup vs baseline: 1.3830x; 1.3830x over previous
//
#include <hip/hip_runtime.h>
#include <hip/hip_bf16.h>

#define NNODE 50000
#define NEDGE 640000
#define NREL  3
#define HIDD  128
#define GNUM  512
#define K1M   128   // layer-1 GEMM K (99 used + pad to 128 for MFMA)
#define K2    512   // layer-2 GEMM K (3*128 relations + 128 root)
#define NB    196   // scan blocks = ceil(NNODE/256)
#define EQ    (NEDGE / 4)           // 160000 edges per ILP batch
#define CNT_BLOCKS ((EQ + 255) / 256)                       // 625
#define TAB_BLOCKS ((K1M * 128 + 33 * 128 + K2 * 128 + 255) / 256)  // 338

typedef float  f32x4   __attribute__((ext_vector_type(4)));
typedef short  vshort8 __attribute__((ext_vector_type(8)));

// swizzled k-block position within a 32-short row (MFMA LDS, conflict-free)
#define SWZ(row, kb) ((((kb) ^ (((row) >> 1) & 3)) << 3))

__device__ __forceinline__ short bf16_rne(float f) {
    unsigned u = __float_as_uint(f);
    return (short)((u + 0x7FFFu + ((u >> 16) & 1u)) >> 16);
}

// ---------------- merged: edge counting (rank atomics, 4/thread) + nf pack + weight builder ----------------
__global__ void count_build_kernel(const int* __restrict__ ei, const int* __restrict__ et,
                                   const int* __restrict__ shape_id, const int* __restrict__ color_id,
                                   const float* __restrict__ pos,
                                   int* __restrict__ cnt, int* __restrict__ rank,
                                   int2* __restrict__ nf,
                                   const float* __restrict__ shape_w, const float* __restrict__ color_w,
                                   const float* __restrict__ W1, const float* __restrict__ root1,
                                   const float* __restrict__ W2, const float* __restrict__ root2,
                                   short* __restrict__ B1th, float* __restrict__ rootTab,
                                   short* __restrict__ Bt_hi) {
    if (blockIdx.x < CNT_BLOCKS) {
        int tid = blockIdx.x * blockDim.x + threadIdx.x;   // 0..EQ-1
        if (tid < NNODE) nf[tid] = make_int2(shape_id[tid] | (color_id[tid] << 8), __float_as_int(pos[tid]));
        if (tid >= EQ) return;
        int e0 = tid, e1 = tid + EQ, e2 = tid + 2 * EQ, e3 = tid + 3 * EQ;
        int d0 = ei[NEDGE + e0], d1 = ei[NEDGE + e1], d2 = ei[NEDGE + e2], d3 = ei[NEDGE + e3];
        int r0 = et[e0], r1 = et[e1], r2 = et[e2], r3 = et[e3];
        int k0 = atomicAdd(&cnt[d0 * 3 + r0], 1);
        int k1 = atomicAdd(&cnt[d1 * 3 + r1], 1);
        int k2 = atomicAdd(&cnt[d2 * 3 + r2], 1);
        int k3 = atomicAdd(&cnt[d3 * 3 + r3], 1);
        rank[e0] = k0; rank[e1] = k1; rank[e2] = k2; rank[e3] = k3;
        return;
    }
    int idx = (blockIdx.x - CNT_BLOCKS) * blockDim.x + threadIdx.x;
    if (idx < K1M * 128) {                    // B1th[n][k]
        int k = idx >> 7, n = idx & 127;
        float v = 0.f;
        if (k < 99) {
            int r = k / 33, j = k - r * 33;
            const float* Wsrc = W1 + (size_t)r * 129 * 128;
            if (j < 16) {
                for (int e = 0; e < 64; ++e) v += shape_w[j * 64 + e] * Wsrc[e * 128 + n];
            } else if (j < 32) {
                int c = j - 16;
                for (int e = 0; e < 64; ++e) v += color_w[c * 64 + e] * Wsrc[(64 + e) * 128 + n];
            } else {
                v = Wsrc[128 * 128 + n];
            }
        }
        B1th[(size_t)n * K1M + k] = bf16_rne(v);
        return;
    }
    int idx2 = idx - K1M * 128;
    if (idx2 < 33 * 128) {                    // rootTab[j][h]
        int h = idx2 & 127, j = idx2 >> 7;
        float v;
        if (j < 16) {
            v = 0.f;
            for (int e = 0; e < 64; ++e) v += shape_w[j * 64 + e] * root1[e * 128 + h];
        } else if (j < 32) {
            int c = j - 16;
            v = 0.f;
            for (int e = 0; e < 64; ++e) v += color_w[c * 64 + e] * root1[(64 + e) * 128 + h];
        } else {
            v = root1[128 * 128 + h];
        }
        rootTab[j * 128 + h] = v;
        return;
    }
    int idx3 = idx2 - 33 * 128;               // Bt_hi[n][k] (B2 transposed)
    if (idx3 >= K2 * 128) return;
    int k = idx3 >> 7, n = idx3 & 127;
    float v = (k < 384) ? W2[idx3] : root2[idx3 - 384 * 128];
    Bt_hi[(size_t)n * K2 + k] = bf16_rne(v);
}

// ---------------- prefix scan (2-phase), relation-major CSR; also zeroes pooled ----------------
__global__ void scan_partial_kernel(const int* __restrict__ cnt, int* __restrict__ partial,
                                    float* __restrict__ pooled) {
    __shared__ int sh[256];
    int t = threadIdx.x, i = blockIdx.x * 256 + t;
    for (int z = i; z < GNUM * 128; z += NB * 256) pooled[z] = 0.f;
    int v = (i < NNODE) ? cnt[3 * i] + cnt[3 * i + 1] + cnt[3 * i + 2] : 0;
    sh[t] = v; __syncthreads();
    for (int o = 128; o > 0; o >>= 1) { if (t < o) sh[t] += sh[t + o]; __syncthreads(); }
    if (t == 0) partial[blockIdx.x] = sh[0];
}

// merged mid+final: each block redundantly scans the 196 partials in LDS
__global__ void scan_final_kernel(const int* __restrict__ cnt, const int* __restrict__ partial,
                                  int* __restrict__ offs3, float* __restrict__ rcnt) {
    __shared__ int shp[256];
    __shared__ int sh[256];
    int t = threadIdx.x, i = blockIdx.x * 256 + t;
    int pv = (t < NB) ? partial[t] : 0;
    shp[t] = pv; __syncthreads();
    for (int o = 1; o < 256; o <<= 1) {
        int x = (t >= o) ? shp[t - o] : 0; __syncthreads();
        shp[t] += x; __syncthreads();
    }
    int blockOff = (blockIdx.x > 0) ? shp[blockIdx.x - 1] : 0;
    int c0 = 0, c1 = 0, c2 = 0;
    if (i < NNODE) { c0 = cnt[3 * i]; c1 = cnt[3 * i + 1]; c2 = cnt[3 * i + 2]; }
    int v = c0 + c1 + c2;
    sh[t] = v; __syncthreads();
    for (int o = 1; o < 256; o <<= 1) {
        int x = (t >= o) ? sh[t - o] : 0; __syncthreads();
        sh[t] += x; __syncthreads();
    }
    int exc = sh[t] - v + blockOff;
    if (i < NNODE) {
        offs3[3 * i]     = exc;
        offs3[3 * i + 1] = exc + c0;
        offs3[3 * i + 2] = exc + c0 + c1;
        float4 rc = make_float4(1.f / fmaxf((float)c0, 1.f), 1.f / fmaxf((float)c1, 1.f),
                                1.f / fmaxf((float)c2, 1.f), 1.f);
        *(float4*)&rcnt[i * 4] = rc;
    }
    if (blockIdx.x == 0 && t == 0) offs3[3 * NNODE] = NEDGE;
}

// ---------------- fill: atomic-free, 4 edges/thread ----------------
__global__ void fill_kernel(const int* __restrict__ ei, const int* __restrict__ et,
                            const int* __restrict__ rank, const int* __restrict__ offs3,
                            int* __restrict__ sorted) {
    int tid = blockIdx.x * blockDim.x + threadIdx.x;   // 0..EQ-1
    if (tid >= EQ) return;
    int e0 = tid, e1 = tid + EQ, e2 = tid + 2 * EQ, e3 = tid + 3 * EQ;
    int s0 = ei[e0], s1 = ei[e1], s2 = ei[e2], s3 = ei[e3];
    int d0 = ei[NEDGE + e0], d1 = ei[NEDGE + e1], d2 = ei[NEDGE + e2], d3 = ei[NEDGE + e3];
    int r0 = et[e0], r1 = et[e1], r2 = et[e2], r3 = et[e3];
    int k0 = rank[e0], k1 = rank[e1], k2 = rank[e2], k3 = rank[e3];
    int p0 = offs3[d0 * 3 + r0] + k0;
    int p1 = offs3[d1 * 3 + r1] + k1;
    int p2 = offs3[d2 * 3 + r2] + k2;
    int p3 = offs3[d3 * 3 + r3] + k3;
    sorted[p0] = s0 | (r0 << 16);
    sorted[p1] = s1 | (r1 << 16);
    sorted[p2] = s2 | (r2 << 16);
    sorted[p3] = s3 | (r3 << 16);
}

// ---------------- layer-1 histogram: edge-parallel, per-wave LDS hist ----------------
__global__ __launch_bounds__(256) void hist1_kernel(const int* __restrict__ offs3,
                                                    const int* __restrict__ sorted,
                                                    const int2* __restrict__ nf,
                                                    const float* __restrict__ rcnt,
                                                    unsigned short* __restrict__ A1h) {
    __shared__ float hist[4][3 * 34];
    int lane = threadIdx.x & 63;
    int wv   = threadIdx.x >> 6;
    int d    = (blockIdx.x << 2) + wv;
    float* hf = hist[wv];
    if (lane < 51) { hf[lane] = 0.f; hf[lane + 51] = 0.f; }
    if (d < NNODE) {
        int beg = offs3[3 * d], end = offs3[3 * d + 3];
        for (int i = beg + lane; i < end; i += 64) {
            int w = sorted[i];
            int s = w & 0xFFFF, r = (w >> 16) & 3;
            int2 f = nf[s];
            atomicAdd(&hf[r * 34 + (f.x & 0xFF)], 1.f);
            atomicAdd(&hf[r * 34 + 16 + (f.x >> 8)], 1.f);
            atomicAdd(&hf[r * 34 + 32], __int_as_float(f.y));
        }
#pragma unroll
        for (int half = 0; half < 2; ++half) {
            int slot = lane + half * 64;                 // 0..127
            float v = 0.f;
            if (slot < 99) {
                int r = slot / 33;
                v = hf[r * 34 + (slot - r * 33)] * rcnt[d * 4 + r];
            }
            A1h[(size_t)d * K1M + slot] = (unsigned short)bf16_rne(v);
        }
    }
}

// ---------------- layer-2 aggregation: wave-per-node, segmented, 8-deep ILP, hi-only ----------------
__global__ __launch_bounds__(256) void aggregate_kernel(const int* __restrict__ offs3,
                                                        const int* __restrict__ sorted,
                                                        const float* __restrict__ rcnt,
                                                        unsigned short* __restrict__ A2h) {
    int lane = threadIdx.x & 63;
    int d = (blockIdx.x << 2) + (threadIdx.x >> 6);
    if (d >= NNODE) return;
    int b0  = __builtin_amdgcn_readfirstlane(offs3[3 * d]);
    int b1  = __builtin_amdgcn_readfirstlane(offs3[3 * d + 1]);
    int b2  = __builtin_amdgcn_readfirstlane(offs3[3 * d + 2]);
    int end = __builtin_amdgcn_readfirstlane(offs3[3 * d + 3]);
    const unsigned* xp = (const unsigned*)A2h;   // row = 256 unsigneds; root block at +192
    float a00 = 0.f, a01 = 0.f, a10 = 0.f, a11 = 0.f, a20 = 0.f, a21 = 0.f;
#define AGG_ACC(ii, x) {                                            \
        float lo_ = __uint_as_float((x) << 16);                     \
        float hi_ = __uint_as_float((x) & 0xFFFF0000u);             \
        if ((ii) >= b2)      { a20 += lo_; a21 += hi_; }            \
        else if ((ii) >= b1) { a10 += lo_; a11 += hi_; }            \
        else                 { a00 += lo_; a01 += hi_; } }
#define AGG_LD(j)  unsigned x##j = xp[((size_t)(unsigned)(sorted[i + j] & 0xFFFF) << 8) + 192 + lane]
    int i = b0;
    for (; i + 8 <= end; i += 8) {
        AGG_LD(0); AGG_LD(1); AGG_LD(2); AGG_LD(3);
        AGG_LD(4); AGG_LD(5); AGG_LD(6); AGG_LD(7);
        AGG_ACC(i, x0); AGG_ACC(i + 1, x1); AGG_ACC(i + 2, x2); AGG_ACC(i + 3, x3);
        AGG_ACC(i + 4, x4); AGG_ACC(i + 5, x5); AGG_ACC(i + 6, x6); AGG_ACC(i + 7, x7);
    }
    for (; i + 4 <= end; i += 4) {
        AGG_LD(0); AGG_LD(1); AGG_LD(2); AGG_LD(3);
        AGG_ACC(i, x0); AGG_ACC(i + 1, x1); AGG_ACC(i + 2, x2); AGG_ACC(i + 3, x3);
    }
    for (; i < end; ++i) {
        AGG_LD(0);
        AGG_ACC(i, x0);
    }
#undef AGG_LD
#undef AGG_ACC
    float rc0 = rcnt[d * 4 + 0], rc1 = rcnt[d * 4 + 1], rc2 = rcnt[d * 4 + 2];
    size_t base = (size_t)d * 512 + (lane << 1);
#define AGG_OUT(vA, vB, rel) {                                        \
        unsigned short h0_ = (unsigned short)bf16_rne(vA);            \
        unsigned short h1_ = (unsigned short)bf16_rne(vB);            \
        *(unsigned*)&A2h[base + (rel) * 128] = (unsigned)h0_ | ((unsigned)h1_ << 16); }
    AGG_OUT(a00 * rc0, a01 * rc0, 0);
    AGG_OUT(a10 * rc1, a11 * rc1, 1);
    AGG_OUT(a20 * rc2, a21 * rc2, 2);
#undef AGG_OUT
}

// ---------------- layer-1 GEMM: MFMA bf16 AhxBh, BM=64, swizzled LDS, fused root epilogue ----------------
__global__ __launch_bounds__(256) void gemm1_mfma_kernel(
    const unsigned short* __restrict__ A1h,
    const short* __restrict__ B1th,
    const int* __restrict__ shape_id, const int* __restrict__ color_id,
    const float* __restrict__ pos, const float* __restrict__ rootTab,
    const float* __restrict__ bias,
    unsigned short* __restrict__ A2h) {
    __shared__ short Ah[64][32];
    __shared__ short Bh[128][32];
    const int t    = threadIdx.x;
    const int lane = t & 63;
    const int w    = t >> 6;
    const int wm   = w >> 1, wn = w & 1;     // wave tile 32(M) x 64(N)
    const int bm0  = blockIdx.x * 64;
    const int lr   = lane & 15, lk = lane >> 4;
    const int sr = t >> 2, skb = t & 3;
    int gra = bm0 + sr; if (gra >= NNODE) gra = NNODE - 1;   // clamp (C-write guarded)
    f32x4 acc[2][4] = {};
    for (int kt = 0; kt < K1M; kt += 32) {
        vshort8 avh = *(const vshort8*)&A1h[(size_t)gra * K1M + kt + skb * 8];
        vshort8 bvh0 = *(const vshort8*)&B1th[(size_t)sr * K1M + kt + skb * 8];
        vshort8 bvh1 = *(const vshort8*)&B1th[(size_t)(sr + 64) * K1M + kt + skb * 8];
        __syncthreads();
        *(vshort8*)&Ah[sr][SWZ(sr, skb)]           = avh;
        *(vshort8*)&Bh[sr][SWZ(sr, skb)]           = bvh0;
        *(vshort8*)&Bh[sr + 64][SWZ(sr + 64, skb)] = bvh1;
        __syncthreads();
        vshort8 afh[2], bfh[4];
#pragma unroll
        for (int mf = 0; mf < 2; ++mf) {
            int row = wm * 32 + mf * 16 + lr;
            afh[mf] = *(const vshort8*)&Ah[row][SWZ(row, lk)];
        }
#pragma unroll
        for (int nf2 = 0; nf2 < 4; ++nf2) {
            int row = wn * 64 + nf2 * 16 + lr;
            bfh[nf2] = *(const vshort8*)&Bh[row][SWZ(row, lk)];
        }
#pragma unroll
        for (int mf = 0; mf < 2; ++mf)
#pragma unroll
            for (int nf2 = 0; nf2 < 4; ++nf2)
                acc[mf][nf2] = __builtin_amdgcn_mfma_f32_16x16x32_bf16(afh[mf], bfh[nf2], acc[mf][nf2], 0, 0, 0);
    }
    // epilogue: + root lookups + bias, relu, write A2 root block (bf16-hi)
#pragma unroll
    for (int mf = 0; mf < 2; ++mf) {
        int mb = bm0 + wm * 32 + mf * 16 + (lane >> 4) * 4;
#pragma unroll
        for (int r = 0; r < 4; ++r) {
            int gm = mb + r;
            if (gm >= NNODE) continue;
            int sid = shape_id[gm], cid = color_id[gm];
            float pv = pos[gm];
#pragma unroll
            for (int nf2 = 0; nf2 < 4; ++nf2) {
                int n = wn * 64 + nf2 * 16 + lr;
                float v = acc[mf][nf2][r] + rootTab[sid * 128 + n] + rootTab[(16 + cid) * 128 + n]
                        + pv * rootTab[32 * 128 + n] + bias[n];
                A2h[(size_t)gm * 512 + 384 + n] = (unsigned short)bf16_rne(fmaxf(v, 0.f));
            }
        }
    }
}

// ---------------- layer-2 GEMM: MFMA bf16 AhxBh, BM=64, swizzled LDS, FUSED POOL epilogue ----------------
__global__ __launch_bounds__(256) void gemm2_mfma_kernel(
    const unsigned short* __restrict__ A2h,
    const short* __restrict__ Bt_hi,
    const float* __restrict__ bias,
    const int* __restrict__ batch,
    float* __restrict__ pooled) {
    __shared__ char smem[64 * 132 * 4 + 256];          // Cst[64][132] f32, union w/ Ah,Bh
    short (*Ah)[32]   = (short(*)[32])smem;            // 4 KB
    short (*Bh)[32]   = (short(*)[32])(smem + 4096);   // 8 KB
    float (*Cst)[132] = (float(*)[132])smem;           // 33.8 KB (after compute)
    int*  batchLDS    = (int*)(smem + 64 * 132 * 4);
    const int t    = threadIdx.x;
    const int lane = t & 63;
    const int w    = t >> 6;
    const int wm   = w >> 1, wn = w & 1;     // wave tile 32(M) x 64(N)
    const int bm0  = blockIdx.x * 64;
    const int lr   = lane & 15, lk = lane >> 4;
    const int sr = t >> 2, skb = t & 3;
    int gra = bm0 + sr; if (gra >= NNODE) gra = NNODE - 1;   // clamp (epilogue guarded)
    f32x4 acc[2][4] = {};
    for (int kt = 0; kt < K2; kt += 32) {
        vshort8 avh = *(const vshort8*)&A2h[(size_t)gra * K2 + kt + skb * 8];
        vshort8 bvh0 = *(const vshort8*)&Bt_hi[(size_t)sr * K2 + kt + skb * 8];
        vshort8 bvh1 = *(const vshort8*)&Bt_hi[(size_t)(sr + 64) * K2 + kt + skb * 8];
        __syncthreads();
        *(vshort8*)&Ah[sr][SWZ(sr, skb)]           = avh;
        *(vshort8*)&Bh[sr][SWZ(sr, skb)]           = bvh0;
        *(vshort8*)&Bh[sr + 64][SWZ(sr + 64, skb)] = bvh1;
        __syncthreads();
        vshort8 afh[2], bfh[4];
#pragma unroll
        for (int mf = 0; mf < 2; ++mf) {
            int row = wm * 32 + mf * 16 + lr;
            afh[mf] = *(const vshort8*)&Ah[row][SWZ(row, lk)];
        }
#pragma unroll
        for (int nf2 = 0; nf2 < 4; ++nf2) {
            int row = wn * 64 + nf2 * 16 + lr;
            bfh[nf2] = *(const vshort8*)&Bh[row][SWZ(row, lk)];
        }
#pragma unroll
        for (int mf = 0; mf < 2; ++mf)
#pragma unroll
            for (int nf2 = 0; nf2 < 4; ++nf2)
                acc[mf][nf2] = __builtin_amdgcn_mfma_f32_16x16x32_bf16(afh[mf], bfh[nf2], acc[mf][nf2], 0, 0, 0);
    }
    __syncthreads();   // all LDS reads done; reuse smem as Cst
    // stage relu(C) to LDS
#pragma unroll
    for (int mf = 0; mf < 2; ++mf) {
        int rb = wm * 32 + mf * 16 + (lane >> 4) * 4;
#pragma unroll
        for (int nf2 = 0; nf2 < 4; ++nf2) {
            int n = wn * 64 + nf2 * 16 + lr;
            float bn = bias[n];
#pragma unroll
            for (int r = 0; r < 4; ++r)
                Cst[rb + r][n] = fmaxf(acc[mf][nf2][r] + bn, 0.f);
        }
    }
    if (t < 64) batchLDS[t] = (bm0 + t < NNODE) ? batch[bm0 + t] : -1;
    __syncthreads();
    // run-length reduce 32 rows per thread -> atomicAdd per (graph, col)
    {
        int col  = t & 127;
        int rbeg = (t >> 7) * 32;
        float accp = 0.f;
        int cur = batchLDS[rbeg];
        for (int rr = 0; rr < 32; ++rr) {
            int row = rbeg + rr;
            int g = batchLDS[row];
            if (g != cur) {
                if (cur >= 0) atomicAdd(&pooled[cur * 128 + col], accp);
                accp = 0.f; cur = g;
            }
            if (g >= 0) accp += Cst[row][col];
        }
        if (cur >= 0) atomicAdd(&pooled[cur * 128 + col], accp);
    }
}

// ---------------- final: per-graph count via binary search on sorted batch ----------------
__global__ void final_kernel(const float* __restrict__ pooled, const int* __restrict__ batch,
                             const float* __restrict__ lin_w, const float* __restrict__ lin_b,
                             float* __restrict__ out) {
    int idx = blockIdx.x * blockDim.x + threadIdx.x;
    if (idx >= GNUM * 4) return;
    int g = idx >> 2, c = idx & 3;
    int lo = 0, hi = NNODE;
    while (lo < hi) { int m = (lo + hi) >> 1; if (batch[m] < g) lo = m + 1; else hi = m; }
    int lo2 = lo, hi2 = NNODE;
    while (lo2 < hi2) { int m = (lo2 + hi2) >> 1; if (batch[m] < g + 1) lo2 = m + 1; else hi2 = m; }
    float cntf = (float)max(lo2 - lo, 1);
    float dot = 0.f;
    for (int k = 0; k < 128; ++k) dot += pooled[g * 128 + k] * lin_w[k * 4 + c];
    out[idx] = dot / cntf + lin_b[c];
}

// ---------------- launch ----------------
extern "C" void kernel_launch(void* const* d_in, const int* in_sizes, int n_in,
                              void* d_out, int out_size, void* d_ws, size_t ws_size,
                              hipStream_t stream) {
    const float* pos      = (const float*)d_in[0];
    const int*   shape_id = (const int*)d_in[1];
    const int*   color_id = (const int*)d_in[2];
    const int*   ei       = (const int*)d_in[3];
    const int*   et       = (const int*)d_in[4];
    const int*   batch    = (const int*)d_in[5];
    const float* shape_w  = (const float*)d_in[6];
    const float* color_w  = (const float*)d_in[7];
    const float* W1       = (const float*)d_in[8];
    const float* root1    = (const float*)d_in[9];
    const float* b1       = (const float*)d_in[10];
    const float* W2       = (const float*)d_in[11];
    const float* root2    = (const float*)d_in[12];
    const float* b2       = (const float*)d_in[13];
    const float* lin_w    = (const float*)d_in[14];
    const float* lin_b    = (const float*)d_in[15];
    float* out = (float*)d_out;

    char* p = (char*)d_ws;
    auto alloc = [&](size_t bytes) { char* r = p; p += (bytes + 255) & ~(size_t)255; return r; };
    int*   cnt     = (int*)alloc((size_t)NNODE * 3 * 4);
    unsigned short* A1h = (unsigned short*)alloc((size_t)NNODE * K1M * 2);
    float* rcntBuf = (float*)alloc((size_t)NNODE * 4 * 4);
    unsigned short* A2h = (unsigned short*)alloc((size_t)NNODE * K2 * 2);
    float* rootTab = (float*)alloc((size_t)33 * 128 * 4);
    short* B1th    = (short*)alloc((size_t)128 * K1M * 2);
    short* Bt_hi   = (short*)alloc((size_t)128 * K2 * 2);
    float* pooled  = (float*)alloc((size_t)GNUM * 128 * 4);
    int2*  nfTab   = (int2*)alloc((size_t)NNODE * 8);
    int*   sorted  = (int*)alloc((size_t)NEDGE * 4);
    int*   offs3   = (int*)alloc((size_t)(3 * NNODE + 1) * 4);
    int*   rank    = (int*)alloc((size_t)NEDGE * 4);
    int*   partial = (int*)alloc((size_t)NB * 4);

    hipMemsetAsync(cnt, 0, (size_t)NNODE * 3 * 4, stream);

    count_build_kernel<<<CNT_BLOCKS + TAB_BLOCKS, 256, 0, stream>>>(
        ei, et, shape_id, color_id, pos, cnt, rank, nfTab,
        shape_w, color_w, W1, root1, W2, root2, B1th, rootTab, Bt_hi);

    scan_partial_kernel<<<NB, 256, 0, stream>>>(cnt, partial, pooled);
    scan_final_kernel<<<NB, 256, 0, stream>>>(cnt, partial, offs3, rcntBuf);
    fill_kernel<<<(EQ + 255) / 256, 256, 0, stream>>>(ei, et, rank, offs3, sorted);

    hist1_kernel<<<(NNODE + 3) / 4, 256, 0, stream>>>(offs3, sorted, nfTab, rcntBuf, A1h);

    gemm1_mfma_kernel<<<(NNODE + 63) / 64, 256, 0, stream>>>(
        A1h, B1th, shape_id, color_id, pos, rootTab, b1, A2h);

    aggregate_kernel<<<(NNODE + 3) / 4, 256, 0, stream>>>(offs3, sorted, rcntBuf, A2h);

    gemm2_mfma_kernel<<<(NNODE + 63) / 64, 256, 0, stream>>>(
        A2h, Bt_hi, b2, batch, pooled);

    final_kernel<<<(GNUM * 4 + 255) / 256, 256, 0, stream>>>(
        pooled, batch, lin_w, lin_b, out);
}